// Round 1
// baseline (1984.817 us; speedup 1.0000x reference)
//
#include <hip/hip_runtime.h>
#include <math.h>

#define NN 10000
#define NI 1000
#define NF 8600
#define NE 80000
#define NC 16
#define NB 64
#define NS (NI + NF)      // 9600 possible src nodes
#define NLAYERS 6
#define LN_EPS 1e-5f

#define EDGE_BLOCKS ((NS + 3) / 4)   // 2400, 4 waves per block
#define NODE_BLOCKS ((NF + 3) / 4)   // 2150

__device__ __forceinline__ float elu(float x) {
    return x > 0.0f ? x : expm1f(x);
}

// xT[n*64+b] = x[b*N+n]
__global__ void k_transpose(const float* __restrict__ x, float* __restrict__ xT) {
    int idx = blockIdx.x * blockDim.x + threadIdx.x;
    if (idx >= NN * NB) return;
    int n = idx >> 6, b = idx & 63;
    xT[idx] = x[b * NN + n];
}

// xe[e*64+b] = x0[e][b]; stats = identity (mu=0, rstd=1)
__global__ void k_init_xe(const float* __restrict__ xT, const int* __restrict__ src,
                          float* __restrict__ xe, float* __restrict__ stats) {
    size_t idx = (size_t)blockIdx.x * blockDim.x + threadIdx.x;
    if (idx < 128) stats[idx] = (idx < 64) ? 0.f : 1.f;
    if (idx >= (size_t)NE * NB) return;
    int e = (int)(idx >> 6), b = (int)(idx & 63);
    xe[idx] = xT[src[e] * NB + b];
}

// h2c = elu(b2) for input-node rows (batch-constant h2)
__global__ void k_h2c(const float* __restrict__ b2, float* __restrict__ h2c) {
    int idx = blockIdx.x * blockDim.x + threadIdx.x;
    if (idx >= NI * NC) return;
    h2c[idx] = elu(b2[idx]);
}

__global__ void k_count(const int* __restrict__ src, const int* __restrict__ dst,
                        int* __restrict__ cs, int* __restrict__ cd) {
    int e = blockIdx.x * blockDim.x + threadIdx.x;
    if (e >= NE) return;
    atomicAdd(&cs[src[e]], 1);
    int d = dst[e];
    if (d >= NI && d < NI + NF) atomicAdd(&cd[d - NI], 1);
}

// single-block exclusive scan (L <= 10240), rp[L] = total
__global__ void k_scan(const int* __restrict__ cnt, int* __restrict__ rp, int L) {
    __shared__ int tsum[1024];
    int t = threadIdx.x;
    int per = (L + 1023) >> 10;
    int beg = t * per;
    int end = beg + per; if (end > L) end = L;
    int s = 0;
    for (int i = beg; i < end; ++i) s += cnt[i];
    tsum[t] = s;
    __syncthreads();
    for (int off = 1; off < 1024; off <<= 1) {
        int v = (t >= off) ? tsum[t - off] : 0;
        __syncthreads();
        tsum[t] += v;
        __syncthreads();
    }
    int run = (t == 0) ? 0 : tsum[t - 1];
    for (int i = beg; i < end; ++i) { rp[i] = run; run += cnt[i]; }
    if (t == 1023) rp[L] = tsum[1023];
}

__global__ void k_copyoff(const int* __restrict__ rp_s, const int* __restrict__ rp_d,
                          int* __restrict__ off_s, int* __restrict__ off_d) {
    int i = blockIdx.x * blockDim.x + threadIdx.x;
    if (i < NS) off_s[i] = rp_s[i];
    if (i < NF) off_d[i] = rp_d[i];
}

__global__ void k_fill(const int* __restrict__ src, const int* __restrict__ dst,
                       int* __restrict__ off_s, int* __restrict__ off_d,
                       int* __restrict__ el_s, int* __restrict__ el_d) {
    int e = blockIdx.x * blockDim.x + threadIdx.x;
    if (e >= NE) return;
    int p = atomicAdd(&off_s[src[e]], 1);
    el_s[p] = e;
    int d = dst[e];
    if (d >= NI && d < NI + NF) {
        int q = atomicAdd(&off_d[d - NI], 1);
        el_d[q] = e;
    }
}

// Per fn node: gather incoming edges (post-blend xe), scatter-sum with w1,
// elu(+b1), 16x16 transform with w2, elu(+b2) -> h2 row.
__global__ __launch_bounds__(256) void k_node(
    const float* __restrict__ xe, const float* __restrict__ xT,
    const float* __restrict__ stats, const float* __restrict__ mask,
    const int* __restrict__ src,
    const float* __restrict__ w1, const float* __restrict__ b1,
    const float* __restrict__ w2, const float* __restrict__ b2,
    const int* __restrict__ rp, const int* __restrict__ el,
    float* __restrict__ h2)
{
    int wid = (blockIdx.x * blockDim.x + threadIdx.x) >> 6;
    int lane = threadIdx.x & 63;
    if (wid >= NF) return;
    int n = NI + wid;
    float mu = stats[lane], rs = stats[64 + lane];

    float acc[NC];
    #pragma unroll
    for (int c = 0; c < NC; ++c) acc[c] = 0.f;

    int k0 = rp[wid], k1 = rp[wid + 1];
    for (int k = k0; k < k1; ++k) {
        int e = el[k];
        int s = src[e];
        float m = mask[e];
        float x0v = xT[s * NB + lane];
        float xn  = (xe[(size_t)e * NB + lane] - mu) * rs;
        float xv  = m * x0v + (1.f - m) * xn;   // post-blend xe of prev layer
        const float4* w1r = (const float4*)(w1 + (size_t)e * NC);
        float wv[NC];
        ((float4*)wv)[0] = w1r[0]; ((float4*)wv)[1] = w1r[1];
        ((float4*)wv)[2] = w1r[2]; ((float4*)wv)[3] = w1r[3];
        #pragma unroll
        for (int c = 0; c < NC; ++c) acc[c] += xv * wv[c];
    }

    float h[NC];
    #pragma unroll
    for (int c = 0; c < NC; ++c) h[c] = elu(acc[c] + b1[n * NC + c]);

    float hf[NC];
    #pragma unroll
    for (int d = 0; d < NC; ++d) hf[d] = 0.f;
    const float* w2f = w2 + (size_t)wid * NC * NC;
    #pragma unroll
    for (int c = 0; c < NC; ++c) {
        const float4* w2r = (const float4*)(w2f + c * NC);
        float wr[NC];
        ((float4*)wr)[0] = w2r[0]; ((float4*)wr)[1] = w2r[1];
        ((float4*)wr)[2] = w2r[2]; ((float4*)wr)[3] = w2r[3];
        float hc = h[c];
        #pragma unroll
        for (int d = 0; d < NC; ++d) hf[d] += hc * wr[d];
    }

    #pragma unroll
    for (int d = 0; d < NC; ++d) {
        float v = elu(hf[d] + b2[n * NC + d]);
        h2[((size_t)wid * NC + d) * NB + lane] = v;
    }
}

// Per src node: load its h2 row once, emit all out-edges:
// v = dot(h2[src], w3[e]) + b3[e] + x_last[e]; accumulate LN partial sums.
__global__ __launch_bounds__(256) void k_edge(
    float* __restrict__ xe, const float* __restrict__ xT,
    const float* __restrict__ stats, const float* __restrict__ mask,
    const float* __restrict__ h2, const float* __restrict__ h2c,
    const float* __restrict__ w3, const float* __restrict__ b3,
    const int* __restrict__ rp, const int* __restrict__ el,
    float* __restrict__ partials)
{
    __shared__ float shs[256], shq[256];
    int wIn = threadIdx.x >> 6;
    int lane = threadIdx.x & 63;
    int s = blockIdx.x * 4 + wIn;
    float lsum = 0.f, lsq = 0.f;
    if (s < NS) {
        float mu = stats[lane], rs = stats[64 + lane];
        float hv[NC];
        if (s < NI) {
            #pragma unroll
            for (int c = 0; c < NC; ++c) hv[c] = h2c[s * NC + c];
        } else {
            int f = s - NI;
            #pragma unroll
            for (int c = 0; c < NC; ++c) hv[c] = h2[((size_t)f * NC + c) * NB + lane];
        }
        float x0v = xT[s * NB + lane];
        int k0 = rp[s], k1 = rp[s + 1];
        for (int k = k0; k < k1; ++k) {
            int e = el[k];
            float m = mask[e];
            float xeo = xe[(size_t)e * NB + lane];
            float xl = m * x0v + (1.f - m) * ((xeo - mu) * rs);
            const float4* w3r = (const float4*)(w3 + (size_t)e * NC);
            float wc[NC];
            ((float4*)wc)[0] = w3r[0]; ((float4*)wc)[1] = w3r[1];
            ((float4*)wc)[2] = w3r[2]; ((float4*)wc)[3] = w3r[3];
            float v = b3[e] + xl;
            #pragma unroll
            for (int c = 0; c < NC; ++c) v += hv[c] * wc[c];
            xe[(size_t)e * NB + lane] = v;
            lsum += v; lsq += v * v;
        }
    }
    shs[threadIdx.x] = lsum; shq[threadIdx.x] = lsq;
    __syncthreads();
    if (threadIdx.x < 64) {
        float ts = shs[lane] + shs[64 + lane] + shs[128 + lane] + shs[192 + lane];
        float tq = shq[lane] + shq[64 + lane] + shq[128 + lane] + shq[192 + lane];
        partials[blockIdx.x * 128 + lane] = ts;
        partials[blockIdx.x * 128 + 64 + lane] = tq;
    }
}

__global__ void k_stats(const float* __restrict__ partials, float* __restrict__ stats, int nb) {
    __shared__ float sh[512];
    int t = threadIdx.x;           // 256 threads
    int lane = t & 63, g = t >> 6;
    float s = 0.f, q = 0.f;
    for (int k = g; k < nb; k += 4) {
        s += partials[k * 128 + lane];
        q += partials[k * 128 + 64 + lane];
    }
    sh[t] = s; sh[256 + t] = q;
    __syncthreads();
    if (t < 64) {
        float ts = sh[t] + sh[64 + t] + sh[128 + t] + sh[192 + t];
        float tq = sh[256 + t] + sh[320 + t] + sh[384 + t] + sh[448 + t];
        float mu = ts / (float)NE;
        float var = tq / (float)NE - mu * mu;
        stats[t] = mu;
        stats[64 + t] = rsqrtf(var + LN_EPS);
    }
}

__global__ void k_out(const float* __restrict__ xe, const float* __restrict__ xT,
                      const float* __restrict__ stats, const float* __restrict__ mask,
                      const int* __restrict__ src,
                      const float* __restrict__ scale, const float* __restrict__ bias,
                      const int* __restrict__ last_edge, const float* __restrict__ has,
                      float* __restrict__ out) {
    int idx = blockIdx.x * blockDim.x + threadIdx.x;
    if (idx >= NB * NN) return;
    int b = idx / NN, n = idx % NN;
    int le = last_edge[n];
    float mu = stats[b], rs = stats[64 + b];
    float m = mask[le];
    float x0v = xT[src[le] * NB + b];
    float xn = (xe[(size_t)le * NB + b] - mu) * rs;
    float xf = m * x0v + (1.f - m) * xn;
    out[idx] = has[n] * (scale[le] * xf + bias[le]);
}

extern "C" void kernel_launch(void* const* d_in, const int* in_sizes, int n_in,
                              void* d_out, int out_size, void* d_ws, size_t ws_size,
                              hipStream_t stream) {
    const float* x     = (const float*)d_in[0];
    const float* w1    = (const float*)d_in[1];
    const float* b1    = (const float*)d_in[2];
    const float* w2    = (const float*)d_in[3];
    const float* b2    = (const float*)d_in[4];
    const float* w3    = (const float*)d_in[5];
    const float* b3    = (const float*)d_in[6];
    const float* scale = (const float*)d_in[7];
    const float* bias  = (const float*)d_in[8];
    const int*   src   = (const int*)d_in[9];
    const int*   dst   = (const int*)d_in[10];
    const float* mask  = (const float*)d_in[12];
    const int*   last  = (const int*)d_in[13];
    const float* has   = (const float*)d_in[14];
    float* out = (float*)d_out;

    char* p = (char*)d_ws;
    auto alloc = [&](size_t bytes) {
        char* r = p;
        p += (bytes + 255) & ~(size_t)255;
        return r;
    };
    float* xe    = (float*)alloc((size_t)NE * NB * 4);
    float* h2    = (float*)alloc((size_t)NF * NC * NB * 4);
    float* xT    = (float*)alloc((size_t)NN * NB * 4);
    float* h2c   = (float*)alloc((size_t)NI * NC * 4);
    float* stats = (float*)alloc(128 * 4);
    float* parts = (float*)alloc((size_t)EDGE_BLOCKS * 128 * 4);
    int* rp_s  = (int*)alloc((NS + 1) * 4);
    int* rp_d  = (int*)alloc((NF + 1) * 4);
    int* el_s  = (int*)alloc((size_t)NE * 4);
    int* el_d  = (int*)alloc((size_t)NE * 4);
    int* off_s = (int*)alloc(NS * 4);
    int* off_d = (int*)alloc(NF * 4);
    int* cs    = (int*)alloc(NS * 4);
    int* cd    = (int*)alloc(NF * 4);

    hipMemsetAsync(cs, 0, NS * 4, stream);
    hipMemsetAsync(cd, 0, NF * 4, stream);
    k_transpose<<<(NN * NB + 255) / 256, 256, 0, stream>>>(x, xT);
    k_count<<<(NE + 255) / 256, 256, 0, stream>>>(src, dst, cs, cd);
    k_scan<<<1, 1024, 0, stream>>>(cs, rp_s, NS);
    k_scan<<<1, 1024, 0, stream>>>(cd, rp_d, NF);
    k_copyoff<<<(NS + 255) / 256, 256, 0, stream>>>(rp_s, rp_d, off_s, off_d);
    k_fill<<<(NE + 255) / 256, 256, 0, stream>>>(src, dst, off_s, off_d, el_s, el_d);
    k_init_xe<<<(int)(((size_t)NE * NB + 255) / 256), 256, 0, stream>>>(xT, src, xe, stats);
    k_h2c<<<(NI * NC + 255) / 256, 256, 0, stream>>>(b2, h2c);

    for (int L = 0; L < NLAYERS; ++L) {
        k_node<<<NODE_BLOCKS, 256, 0, stream>>>(xe, xT, stats, mask, src,
                                                w1, b1, w2, b2, rp_d, el_d, h2);
        k_edge<<<EDGE_BLOCKS, 256, 0, stream>>>(xe, xT, stats, mask, h2, h2c,
                                                w3, b3, rp_s, el_s, parts);
        k_stats<<<1, 256, 0, stream>>>(parts, stats, EDGE_BLOCKS);
    }
    k_out<<<(NB * NN + 255) / 256, 256, 0, stream>>>(xe, xT, stats, mask, src,
                                                     scale, bias, last, has, out);
}

// Round 2
// 1071.383 us; speedup vs baseline: 1.8526x; 1.8526x over previous
//
#include <hip/hip_runtime.h>
#include <math.h>

#define NN 10000
#define NI 1000
#define NF 8600
#define NE 80000
#define NC 16
#define NB 64
#define NS (NI + NF)      // 9600 possible src nodes
#define NLAYERS 6
#define LN_EPS 1e-5f

#define NODE_BLOCKS ((NF + 3) / 4)       // 2150 blocks x 4 waves
#define EDGE_BLOCKS ((NS + 7) / 8)       // 1200 blocks x 8 waves
#define TILE_BLOCKS ((NN + 63) / 64)     // 157

__device__ __forceinline__ float elu(float x) {
    return x > 0.0f ? x : expm1f(x);
}

// ---- tiled transpose: xT[n*64+b] = x[b*NN+n] ----
__global__ __launch_bounds__(256) void k_transpose(const float* __restrict__ x,
                                                   float* __restrict__ xT) {
    __shared__ float t[64][65];
    int n0 = blockIdx.x * 64;
    int lane = threadIdx.x & 63, w = threadIdx.x >> 6;
    int n = n0 + lane;
    for (int bb = w; bb < 64; bb += 4)
        t[bb][lane] = (n < NN) ? x[(size_t)bb * NN + n] : 0.f;
    __syncthreads();
    for (int nn = w; nn < 64; nn += 4) {
        int nw = n0 + nn;
        if (nw < NN) xT[(size_t)nw * 64 + lane] = t[lane][nn];
    }
}

// xe[e*64+b] = x0(src[e])[b]; accum init: slot0 = identity stats, rest 0
__global__ void k_init_xe(const float* __restrict__ xT, const int* __restrict__ src,
                          float* __restrict__ xe, float* __restrict__ accum) {
    size_t idx = (size_t)blockIdx.x * blockDim.x + threadIdx.x;
    if (idx < (NLAYERS + 1) * 128) {
        float v = 0.f;
        if (idx >= 64 && idx < 128) v = (float)NE * (1.0f - LN_EPS);
        accum[idx] = v;
    }
    if (idx >= (size_t)NE * NB) return;
    int e = (int)(idx >> 6), b = (int)(idx & 63);
    xe[idx] = xT[(size_t)src[e] * NB + b];
}

__global__ void k_h2c(const float* __restrict__ b2, float* __restrict__ h2c) {
    int idx = blockIdx.x * blockDim.x + threadIdx.x;
    if (idx >= NI * NC) return;
    h2c[idx] = elu(b2[idx]);
}

__global__ void k_count(const int* __restrict__ src, const int* __restrict__ dst,
                        int* __restrict__ cs, int* __restrict__ cd) {
    int e = blockIdx.x * blockDim.x + threadIdx.x;
    if (e >= NE) return;
    atomicAdd(&cs[src[e]], 1);
    int d = dst[e];
    if (d >= NI && d < NI + NF) atomicAdd(&cd[d - NI], 1);
}

__global__ void k_scan(const int* __restrict__ cnt, int* __restrict__ rp, int L) {
    __shared__ int tsum[1024];
    int t = threadIdx.x;
    int per = (L + 1023) >> 10;
    int beg = t * per;
    int end = beg + per; if (end > L) end = L;
    int s = 0;
    for (int i = beg; i < end; ++i) s += cnt[i];
    tsum[t] = s;
    __syncthreads();
    for (int off = 1; off < 1024; off <<= 1) {
        int v = (t >= off) ? tsum[t - off] : 0;
        __syncthreads();
        tsum[t] += v;
        __syncthreads();
    }
    int run = (t == 0) ? 0 : tsum[t - 1];
    for (int i = beg; i < end; ++i) { rp[i] = run; run += cnt[i]; }
    if (t == 1023) rp[L] = tsum[1023];
}

__global__ void k_copyoff(const int* __restrict__ rp_s, const int* __restrict__ rp_d,
                          int* __restrict__ off_s, int* __restrict__ off_d) {
    int i = blockIdx.x * blockDim.x + threadIdx.x;
    if (i < NS) off_s[i] = rp_s[i];
    if (i < NF) off_d[i] = rp_d[i];
}

__global__ void k_fill(const int* __restrict__ src, const int* __restrict__ dst,
                       int* __restrict__ off_s, int* __restrict__ off_d,
                       int* __restrict__ el_s, int* __restrict__ el_d) {
    int e = blockIdx.x * blockDim.x + threadIdx.x;
    if (e >= NE) return;
    int p = atomicAdd(&off_s[src[e]], 1);
    el_s[p] = e;
    int d = dst[e];
    if (d >= NI && d < NI + NF) {
        int q = atomicAdd(&off_d[d - NI], 1);
        el_d[q] = e;
    }
}

// Build CSR-ordered packed descriptors + permuted weights (once per call).
// pd[k] = (e<<15)|(src<<1)|maskbit   (e<2^17, src<2^14)
// pe[k] = (e<<1)|maskbit
__global__ void k_permute(const int* __restrict__ src, const float* __restrict__ mask,
                          const float* __restrict__ w1, const float* __restrict__ w3,
                          const float* __restrict__ b3,
                          const int* __restrict__ rp_d,
                          const int* __restrict__ el_d, const int* __restrict__ el_s,
                          unsigned* __restrict__ pd, unsigned* __restrict__ pe,
                          float* __restrict__ w1g, float* __restrict__ w3g,
                          float* __restrict__ b3g) {
    int k = blockIdx.x * blockDim.x + threadIdx.x;
    if (k >= NE) return;
    {
        int e = el_s[k];
        unsigned mb = (mask[e] != 0.f) ? 1u : 0u;
        pe[k] = ((unsigned)e << 1) | mb;
        const float4* s4 = (const float4*)(w3 + (size_t)e * NC);
        float4* d4 = (float4*)(w3g + (size_t)k * NC);
        d4[0] = s4[0]; d4[1] = s4[1]; d4[2] = s4[2]; d4[3] = s4[3];
        b3g[k] = b3[e];
    }
    if (k < rp_d[NF]) {
        int e = el_d[k];
        int s = src[e];
        unsigned mb = (mask[e] != 0.f) ? 1u : 0u;
        pd[k] = ((unsigned)e << 15) | ((unsigned)s << 1) | mb;
        const float4* s4 = (const float4*)(w1 + (size_t)e * NC);
        float4* d4 = (float4*)(w1g + (size_t)k * NC);
        d4[0] = s4[0]; d4[1] = s4[1]; d4[2] = s4[2]; d4[3] = s4[3];
    }
}

// Per fn node (one wave, lane=batch): gather blended in-edge messages, elu(+b1),
// 16x16 w2 transform, elu(+b2) -> h2[f][lane][c]
__global__ __launch_bounds__(256) void k_node(
    const float* __restrict__ xe, const float* __restrict__ xT,
    const float* __restrict__ sums,
    const float* __restrict__ w1g, const float* __restrict__ b1,
    const float* __restrict__ w2, const float* __restrict__ b2,
    const int* __restrict__ rp, const unsigned* __restrict__ pd,
    float* __restrict__ h2)
{
    int wid = (blockIdx.x * blockDim.x + threadIdx.x) >> 6;
    int lane = threadIdx.x & 63;
    if (wid >= NF) return;
    int n = NI + wid;
    const float inv = 1.0f / (float)NE;
    float mu = sums[lane] * inv;
    float rs = rsqrtf(sums[64 + lane] * inv - mu * mu + LN_EPS);

    float acc[NC];
    #pragma unroll
    for (int c = 0; c < NC; ++c) acc[c] = 0.f;

    int k0 = rp[wid], k1 = rp[wid + 1];
    unsigned p0 = 0, p1 = 0;
    float xe0 = 0.f, x00 = 0.f;
    if (k0 < k1) {
        p0 = pd[k0];
        xe0 = xe[(size_t)(p0 >> 15) * NB + lane];
        x00 = xT[(size_t)((p0 >> 1) & 0x3FFFu) * NB + lane];
        if (k0 + 1 < k1) p1 = pd[k0 + 1];
    }
    for (int k = k0; k < k1; ++k) {
        unsigned p2 = (k + 2 < k1) ? pd[k + 2] : 0u;
        float xe1 = 0.f, x01 = 0.f;
        if (k + 1 < k1) {
            xe1 = xe[(size_t)(p1 >> 15) * NB + lane];
            x01 = xT[(size_t)((p1 >> 1) & 0x3FFFu) * NB + lane];
        }
        float xv = (p0 & 1u) ? x00 : (xe0 - mu) * rs;
        const float4* wr = (const float4*)(w1g + (size_t)k * NC);
        float4 a = wr[0], b = wr[1], c = wr[2], d = wr[3];
        acc[0]  += xv * a.x; acc[1]  += xv * a.y; acc[2]  += xv * a.z; acc[3]  += xv * a.w;
        acc[4]  += xv * b.x; acc[5]  += xv * b.y; acc[6]  += xv * b.z; acc[7]  += xv * b.w;
        acc[8]  += xv * c.x; acc[9]  += xv * c.y; acc[10] += xv * c.z; acc[11] += xv * c.w;
        acc[12] += xv * d.x; acc[13] += xv * d.y; acc[14] += xv * d.z; acc[15] += xv * d.w;
        p0 = p1; p1 = p2; xe0 = xe1; x00 = x01;
    }

    float h[NC];
    const float4* b1r = (const float4*)(b1 + (size_t)n * NC);
    {
        float4 a = b1r[0], b = b1r[1], c = b1r[2], d = b1r[3];
        h[0]  = elu(acc[0]  + a.x); h[1]  = elu(acc[1]  + a.y);
        h[2]  = elu(acc[2]  + a.z); h[3]  = elu(acc[3]  + a.w);
        h[4]  = elu(acc[4]  + b.x); h[5]  = elu(acc[5]  + b.y);
        h[6]  = elu(acc[6]  + b.z); h[7]  = elu(acc[7]  + b.w);
        h[8]  = elu(acc[8]  + c.x); h[9]  = elu(acc[9]  + c.y);
        h[10] = elu(acc[10] + c.z); h[11] = elu(acc[11] + c.w);
        h[12] = elu(acc[12] + d.x); h[13] = elu(acc[13] + d.y);
        h[14] = elu(acc[14] + d.z); h[15] = elu(acc[15] + d.w);
    }

    float hf[NC];
    #pragma unroll
    for (int d = 0; d < NC; ++d) hf[d] = 0.f;
    const float* w2f = w2 + (size_t)wid * NC * NC;
    #pragma unroll
    for (int c = 0; c < NC; ++c) {
        const float4* w2r = (const float4*)(w2f + c * NC);
        float4 a = w2r[0], b = w2r[1], cc = w2r[2], d = w2r[3];
        float hc = h[c];
        hf[0]  += hc * a.x;  hf[1]  += hc * a.y;  hf[2]  += hc * a.z;  hf[3]  += hc * a.w;
        hf[4]  += hc * b.x;  hf[5]  += hc * b.y;  hf[6]  += hc * b.z;  hf[7]  += hc * b.w;
        hf[8]  += hc * cc.x; hf[9]  += hc * cc.y; hf[10] += hc * cc.z; hf[11] += hc * cc.w;
        hf[12] += hc * d.x;  hf[13] += hc * d.y;  hf[14] += hc * d.z;  hf[15] += hc * d.w;
    }

    const float4* b2r = (const float4*)(b2 + (size_t)n * NC);
    float4 ba = b2r[0], bb = b2r[1], bc = b2r[2], bd = b2r[3];
    float4 o0, o1, o2, o3;
    o0.x = elu(hf[0]  + ba.x); o0.y = elu(hf[1]  + ba.y);
    o0.z = elu(hf[2]  + ba.z); o0.w = elu(hf[3]  + ba.w);
    o1.x = elu(hf[4]  + bb.x); o1.y = elu(hf[5]  + bb.y);
    o1.z = elu(hf[6]  + bb.z); o1.w = elu(hf[7]  + bb.w);
    o2.x = elu(hf[8]  + bc.x); o2.y = elu(hf[9]  + bc.y);
    o2.z = elu(hf[10] + bc.z); o2.w = elu(hf[11] + bc.w);
    o3.x = elu(hf[12] + bd.x); o3.y = elu(hf[13] + bd.y);
    o3.z = elu(hf[14] + bd.z); o3.w = elu(hf[15] + bd.w);
    float4* h2r = (float4*)(h2 + ((size_t)wid * NB + lane) * NC);
    h2r[0] = o0; h2r[1] = o1; h2r[2] = o2; h2r[3] = o3;
}

// Per src node (one wave, lane=batch): h2 row reused across out-edges.
// v = dot(h2row, w3g[k]) + b3g[k] + x_last; write raw xe; atomic LN sums.
__global__ __launch_bounds__(512) void k_edge(
    float* __restrict__ xe, const float* __restrict__ xT,
    const float* __restrict__ sums, float* __restrict__ sumsOut,
    const float* __restrict__ h2, const float* __restrict__ h2c,
    const float* __restrict__ w3g, const float* __restrict__ b3g,
    const int* __restrict__ rp, const unsigned* __restrict__ pe)
{
    __shared__ float shs[512], shq[512];
    int wIn = threadIdx.x >> 6;
    int lane = threadIdx.x & 63;
    int s = blockIdx.x * 8 + wIn;
    float lsum = 0.f, lsq = 0.f;
    if (s < NS) {
        const float inv = 1.0f / (float)NE;
        float mu = sums[lane] * inv;
        float rs = rsqrtf(sums[64 + lane] * inv - mu * mu + LN_EPS);
        float hv[NC];
        if (s < NI) {
            const float4* hr = (const float4*)(h2c + (size_t)s * NC);
            float4 a = hr[0], b = hr[1], c = hr[2], d = hr[3];
            hv[0]=a.x; hv[1]=a.y; hv[2]=a.z; hv[3]=a.w;
            hv[4]=b.x; hv[5]=b.y; hv[6]=b.z; hv[7]=b.w;
            hv[8]=c.x; hv[9]=c.y; hv[10]=c.z; hv[11]=c.w;
            hv[12]=d.x; hv[13]=d.y; hv[14]=d.z; hv[15]=d.w;
        } else {
            const float4* hr = (const float4*)(h2 + ((size_t)(s - NI) * NB + lane) * NC);
            float4 a = hr[0], b = hr[1], c = hr[2], d = hr[3];
            hv[0]=a.x; hv[1]=a.y; hv[2]=a.z; hv[3]=a.w;
            hv[4]=b.x; hv[5]=b.y; hv[6]=b.z; hv[7]=b.w;
            hv[8]=c.x; hv[9]=c.y; hv[10]=c.z; hv[11]=c.w;
            hv[12]=d.x; hv[13]=d.y; hv[14]=d.z; hv[15]=d.w;
        }
        float x0v = xT[(size_t)s * NB + lane];
        int k0 = rp[s], k1 = rp[s + 1];
        unsigned p0 = 0, p1 = 0;
        float xo0 = 0.f;
        if (k0 < k1) {
            p0 = pe[k0];
            xo0 = xe[(size_t)(p0 >> 1) * NB + lane];
            if (k0 + 1 < k1) p1 = pe[k0 + 1];
        }
        for (int k = k0; k < k1; ++k) {
            unsigned p2 = (k + 2 < k1) ? pe[k + 2] : 0u;
            float xo1 = 0.f;
            if (k + 1 < k1) xo1 = xe[(size_t)(p1 >> 1) * NB + lane];
            float xl = (p0 & 1u) ? x0v : (xo0 - mu) * rs;
            const float4* wr = (const float4*)(w3g + (size_t)k * NC);
            float4 a = wr[0], b = wr[1], c = wr[2], d = wr[3];
            float v = b3g[k] + xl;
            v += hv[0]*a.x + hv[1]*a.y + hv[2]*a.z + hv[3]*a.w;
            v += hv[4]*b.x + hv[5]*b.y + hv[6]*b.z + hv[7]*b.w;
            v += hv[8]*c.x + hv[9]*c.y + hv[10]*c.z + hv[11]*c.w;
            v += hv[12]*d.x + hv[13]*d.y + hv[14]*d.z + hv[15]*d.w;
            xe[(size_t)(p0 >> 1) * NB + lane] = v;
            lsum += v; lsq += v * v;
            p0 = p1; p1 = p2; xo0 = xo1;
        }
    }
    shs[threadIdx.x] = lsum; shq[threadIdx.x] = lsq;
    __syncthreads();
    int t = threadIdx.x;
    if (t < 64) {
        float ts = 0.f;
        #pragma unroll
        for (int w = 0; w < 8; ++w) ts += shs[w * 64 + t];
        atomicAdd(&sumsOut[t], ts);
    } else if (t < 128) {
        int l = t - 64;
        float tq = 0.f;
        #pragma unroll
        for (int w = 0; w < 8; ++w) tq += shq[w * 64 + l];
        atomicAdd(&sumsOut[64 + l], tq);
    }
}

// out[b*NN+n] = has[n]*(scale[le]*blend(norm(xe[le]))+bias[le]), tiled transpose
__global__ __launch_bounds__(256) void k_out(
    const float* __restrict__ xe, const float* __restrict__ xT,
    const float* __restrict__ sums, const float* __restrict__ mask,
    const int* __restrict__ src,
    const float* __restrict__ scale, const float* __restrict__ bias,
    const int* __restrict__ last_edge, const float* __restrict__ has,
    float* __restrict__ out)
{
    __shared__ float t[64][65];
    int n0 = blockIdx.x * 64;
    int lane = threadIdx.x & 63, w = threadIdx.x >> 6;
    const float inv = 1.0f / (float)NE;
    float mu = sums[lane] * inv;
    float rs = rsqrtf(sums[64 + lane] * inv - mu * mu + LN_EPS);
    for (int nn = w; nn < 64; nn += 4) {
        int n = n0 + nn;
        float val = 0.f;
        if (n < NN) {
            int le = last_edge[n];
            float m = mask[le];
            float x0v = xT[(size_t)src[le] * NB + lane];
            float xn = (xe[(size_t)le * NB + lane] - mu) * rs;
            float xf = m * x0v + (1.f - m) * xn;
            val = has[n] * (scale[le] * xf + bias[le]);
        }
        t[nn][lane] = val;
    }
    __syncthreads();
    for (int bb = w; bb < 64; bb += 4) {
        int n = n0 + lane;
        if (n < NN) out[(size_t)bb * NN + n] = t[lane][bb];
    }
}

extern "C" void kernel_launch(void* const* d_in, const int* in_sizes, int n_in,
                              void* d_out, int out_size, void* d_ws, size_t ws_size,
                              hipStream_t stream) {
    const float* x     = (const float*)d_in[0];
    const float* w1    = (const float*)d_in[1];
    const float* b1    = (const float*)d_in[2];
    const float* w2    = (const float*)d_in[3];
    const float* b2    = (const float*)d_in[4];
    const float* w3    = (const float*)d_in[5];
    const float* b3    = (const float*)d_in[6];
    const float* scale = (const float*)d_in[7];
    const float* bias  = (const float*)d_in[8];
    const int*   src   = (const int*)d_in[9];
    const int*   dst   = (const int*)d_in[10];
    const float* mask  = (const float*)d_in[12];
    const int*   last  = (const int*)d_in[13];
    const float* has   = (const float*)d_in[14];
    float* out = (float*)d_out;

    char* p = (char*)d_ws;
    auto alloc = [&](size_t bytes) {
        char* r = p;
        p += (bytes + 255) & ~(size_t)255;
        return r;
    };
    float* xe    = (float*)alloc((size_t)NE * NB * 4);
    float* h2    = (float*)alloc((size_t)NF * NB * NC * 4);
    float* xT    = (float*)alloc((size_t)NN * NB * 4);
    float* h2c   = (float*)alloc((size_t)NI * NC * 4);
    float* accum = (float*)alloc((NLAYERS + 1) * 128 * 4);
    float* w1g   = (float*)alloc((size_t)NE * NC * 4);
    float* w3g   = (float*)alloc((size_t)NE * NC * 4);
    float* b3g   = (float*)alloc((size_t)NE * 4);
    unsigned* pd = (unsigned*)alloc((size_t)NE * 4);
    unsigned* pe = (unsigned*)alloc((size_t)NE * 4);
    int* rp_s  = (int*)alloc((NS + 1) * 4);
    int* rp_d  = (int*)alloc((NF + 1) * 4);
    int* el_s  = (int*)alloc((size_t)NE * 4);
    int* el_d  = (int*)alloc((size_t)NE * 4);
    int* off_s = (int*)alloc(NS * 4);
    int* off_d = (int*)alloc(NF * 4);
    int* cs    = (int*)alloc(NS * 4);
    int* cd    = (int*)alloc(NF * 4);

    hipMemsetAsync(cs, 0, NS * 4, stream);
    hipMemsetAsync(cd, 0, NF * 4, stream);
    k_transpose<<<TILE_BLOCKS, 256, 0, stream>>>(x, xT);
    k_count<<<(NE + 255) / 256, 256, 0, stream>>>(src, dst, cs, cd);
    k_scan<<<1, 1024, 0, stream>>>(cs, rp_s, NS);
    k_scan<<<1, 1024, 0, stream>>>(cd, rp_d, NF);
    k_copyoff<<<(NS + 255) / 256, 256, 0, stream>>>(rp_s, rp_d, off_s, off_d);
    k_fill<<<(NE + 255) / 256, 256, 0, stream>>>(src, dst, off_s, off_d, el_s, el_d);
    k_permute<<<(NE + 255) / 256, 256, 0, stream>>>(src, mask, w1, w3, b3, rp_d,
                                                    el_d, el_s, pd, pe, w1g, w3g, b3g);
    k_init_xe<<<(int)(((size_t)NE * NB + 255) / 256), 256, 0, stream>>>(xT, src, xe, accum);
    k_h2c<<<(NI * NC + 255) / 256, 256, 0, stream>>>(b2, h2c);

    for (int L = 0; L < NLAYERS; ++L) {
        k_node<<<NODE_BLOCKS, 256, 0, stream>>>(xe, xT, accum + L * 128,
                                                w1g, b1, w2, b2, rp_d, pd, h2);
        k_edge<<<EDGE_BLOCKS, 512, 0, stream>>>(xe, xT, accum + L * 128,
                                                accum + (L + 1) * 128,
                                                h2, h2c, w3g, b3g, rp_s, pe);
    }
    k_out<<<TILE_BLOCKS, 256, 0, stream>>>(xe, xT, accum + NLAYERS * 128, mask, src,
                                           scale, bias, last, has, out);
}

// Round 4
// 554.917 us; speedup vs baseline: 3.5768x; 1.9307x over previous
//
#include <hip/hip_runtime.h>
#include <math.h>

#define NN 10000
#define NI 1000
#define NF 8600
#define NE 80000
#define NC 16
#define NB 64
#define NS (NI + NF)        // 9600 possible src nodes
#define NLAYERS 6
#define LN_EPS 1e-5f
#define XEBASE (NN * NB)    // xeD starts here inside xbuf (element offset)

#define NODE_BLOCKS ((NF + 3) / 4)       // 2150 blocks x 4 waves
#define EDGE_BLOCKS ((NS + 7) / 8)       // 1200 blocks x 8 waves
#define TILE_BLOCKS ((NN + 63) / 64)     // 157

typedef float f32x4 __attribute__((ext_vector_type(4)));

__device__ __forceinline__ float elu_fast(float x) {
    // exp(x)-1 for x<=0: abs err ~1ulp(1.0) ~6e-8, fine vs 0.17 threshold
    return x > 0.0f ? x : __expf(x) - 1.0f;
}

// ---- tiled transpose: xbuf[n*64+b] = x[b*NN+n] ----
__global__ __launch_bounds__(256) void k_transpose(const float* __restrict__ x,
                                                   float* __restrict__ xT) {
    __shared__ float t[64][65];
    int n0 = blockIdx.x * 64;
    int lane = threadIdx.x & 63, w = threadIdx.x >> 6;
    int n = n0 + lane;
    for (int bb = w; bb < 64; bb += 4)
        t[bb][lane] = (n < NN) ? x[(size_t)bb * NN + n] : 0.f;
    __syncthreads();
    for (int nn = w; nn < 64; nn += 4) {
        int nw = n0 + nn;
        if (nw < NN) xT[(size_t)nw * 64 + lane] = t[lane][nn];
    }
}

__global__ void k_count(const int* __restrict__ src, const int* __restrict__ dst,
                        int* __restrict__ cs, int* __restrict__ cd) {
    int e = blockIdx.x * blockDim.x + threadIdx.x;
    if (e >= NE) return;
    atomicAdd(&cs[src[e]], 1);
    int d = dst[e];
    if (d >= NI && d < NI + NF) atomicAdd(&cd[d - NI], 1);
}

__global__ void k_scan(const int* __restrict__ cnt, int* __restrict__ rp, int L) {
    __shared__ int tsum[1024];
    int t = threadIdx.x;
    int per = (L + 1023) >> 10;
    int beg = t * per;
    int end = beg + per; if (end > L) end = L;
    int s = 0;
    for (int i = beg; i < end; ++i) s += cnt[i];
    tsum[t] = s;
    __syncthreads();
    for (int off = 1; off < 1024; off <<= 1) {
        int v = (t >= off) ? tsum[t - off] : 0;
        __syncthreads();
        tsum[t] += v;
        __syncthreads();
    }
    int run = (t == 0) ? 0 : tsum[t - 1];
    for (int i = beg; i < end; ++i) { rp[i] = run; run += cnt[i]; }
    if (t == 1023) rp[L] = tsum[1023];
}

__global__ void k_copyoff(const int* __restrict__ rp_s, const int* __restrict__ rp_d,
                          int* __restrict__ off_s, int* __restrict__ off_d,
                          int* __restrict__ foCtr) {
    int i = blockIdx.x * blockDim.x + threadIdx.x;
    if (i < NS) off_s[i] = rp_s[i];
    if (i < NF) off_d[i] = rp_d[i];
    if (i == 0) foCtr[0] = rp_d[NF];
}

__global__ void k_fill(const int* __restrict__ src, const int* __restrict__ dst,
                       int* __restrict__ off_s, int* __restrict__ off_d,
                       int* __restrict__ foCtr,
                       int* __restrict__ el_s, int* __restrict__ el_d,
                       int* __restrict__ posOf) {
    int e = blockIdx.x * blockDim.x + threadIdx.x;
    if (e >= NE) return;
    int p = atomicAdd(&off_s[src[e]], 1);
    el_s[p] = e;
    int d = dst[e];
    int q;
    if (d >= NI && d < NI + NF) {
        q = atomicAdd(&off_d[d - NI], 1);
        el_d[q] = e;
    } else {
        q = atomicAdd(foCtr, 1);   // fo edges: slots after rp_d[NF]
    }
    posOf[e] = q;
}

// Build CSR-ordered streams (once per call).
// pd[k]  (dst order): (off<<1)|normflag ; off = src*64 (input src) or XEBASE+k*64
// pe2[k] (src order): posOf(e)*64
// c3[k]  (src order): b3[e] + dot(elu(b2[src]), w3row) for input-src edges
__global__ void k_permute(const int* __restrict__ src,
                          const float* __restrict__ w1, const float* __restrict__ w3,
                          const float* __restrict__ b3, const float* __restrict__ b2,
                          const int* __restrict__ rp_d,
                          const int* __restrict__ el_d, const int* __restrict__ el_s,
                          const int* __restrict__ posOf,
                          unsigned* __restrict__ pd, unsigned* __restrict__ pe2,
                          float* __restrict__ w1g, float* __restrict__ w3g,
                          float* __restrict__ b3g, float* __restrict__ c3) {
    int k = blockIdx.x * blockDim.x + threadIdx.x;
    if (k >= NE) return;
    {
        int e = el_s[k];
        int s = src[e];
        pe2[k] = (unsigned)(posOf[e] * NB);
        float wrow[NC];
        const f32x4* s4 = (const f32x4*)(w3 + (size_t)e * NC);
        ((f32x4*)wrow)[0] = s4[0]; ((f32x4*)wrow)[1] = s4[1];
        ((f32x4*)wrow)[2] = s4[2]; ((f32x4*)wrow)[3] = s4[3];
        f32x4* d4 = (f32x4*)(w3g + (size_t)k * NC);
        d4[0] = ((f32x4*)wrow)[0]; d4[1] = ((f32x4*)wrow)[1];
        d4[2] = ((f32x4*)wrow)[2]; d4[3] = ((f32x4*)wrow)[3];
        float bb = b3[e];
        b3g[k] = bb;
        float cc = 0.f;
        if (s < NI) {
            const float* b2r = b2 + (size_t)s * NC;
            #pragma unroll
            for (int c = 0; c < NC; ++c) {
                float h = b2r[c];
                h = h > 0.f ? h : __expf(h) - 1.0f;
                cc += h * wrow[c];
            }
            cc += bb;
        }
        c3[k] = cc;
    }
    if (k < rp_d[NF]) {
        int e = el_d[k];
        int s = src[e];
        unsigned off = (s < NI) ? (unsigned)(s * NB) : (unsigned)(XEBASE + k * NB);
        pd[k] = (off << 1) | (s < NI ? 0u : 1u);
        const f32x4* s4 = (const f32x4*)(w1 + (size_t)e * NC);
        f32x4* d4 = (f32x4*)(w1g + (size_t)k * NC);
        d4[0] = s4[0]; d4[1] = s4[1]; d4[2] = s4[2]; d4[3] = s4[3];
    }
}

// xeD[posOf(e)] = x0(src[e]); accum slot0 = identity stats, rest 0
__global__ void k_init_xe(const float* __restrict__ xbuf, const int* __restrict__ src,
                          const int* __restrict__ posOf,
                          float* __restrict__ xeD, float* __restrict__ accum) {
    size_t idx = (size_t)blockIdx.x * blockDim.x + threadIdx.x;
    if (idx < (NLAYERS + 1) * 128) {
        float v = 0.f;
        if (idx >= 64 && idx < 128) v = (float)NE * (1.0f - LN_EPS);
        accum[idx] = v;
    }
    if (idx >= (size_t)NE * NB) return;
    int e = (int)(idx >> 6), b = (int)(idx & 63);
    float v = xbuf[(size_t)src[e] * NB + b];
    __builtin_nontemporal_store(v, &xeD[(size_t)posOf[e] * NB + b]);
}

// Per fn node (one wave, lane=batch): stream in-edge messages (dst-CSR order!),
// blend/norm via fused offset, elu(+b1), 16x16 w2, elu(+b2) -> h2 row (NT).
__global__ __launch_bounds__(256, 4) void k_node(
    const float* __restrict__ xbuf, const float* __restrict__ sums,
    const float* __restrict__ w1g, const float* __restrict__ b1,
    const float* __restrict__ w2, const float* __restrict__ b2,
    const int* __restrict__ rp, const unsigned* __restrict__ pd,
    float* __restrict__ h2)
{
    int wid = __builtin_amdgcn_readfirstlane((int)((blockIdx.x * blockDim.x + threadIdx.x) >> 6));
    int lane = threadIdx.x & 63;
    if (wid >= NF) return;
    const float inv = 1.0f / (float)NE;
    float mu = sums[lane] * inv;
    float rs = rsqrtf(sums[64 + lane] * inv - mu * mu + LN_EPS);

    int n = NI + wid;
    float acc[NC];
    {
        const f32x4* b1r = (const f32x4*)(b1 + (size_t)n * NC);
        f32x4 a = b1r[0], b = b1r[1], c = b1r[2], d = b1r[3];
        acc[0]=a.x; acc[1]=a.y; acc[2]=a.z; acc[3]=a.w;
        acc[4]=b.x; acc[5]=b.y; acc[6]=b.z; acc[7]=b.w;
        acc[8]=c.x; acc[9]=c.y; acc[10]=c.z; acc[11]=c.w;
        acc[12]=d.x; acc[13]=d.y; acc[14]=d.z; acc[15]=d.w;
    }

    int k0 = __builtin_amdgcn_readfirstlane(rp[wid]);
    int k1 = __builtin_amdgcn_readfirstlane(rp[wid + 1]);

    // pipeline: pd 2 ahead, value + w1 row 1 ahead
    unsigned pC = 0, pN = 0;
    float rawC = 0.f;
    f32x4 wC0 = 0.f, wC1 = 0.f, wC2 = 0.f, wC3 = 0.f;
    if (k0 < k1) {
        pC = pd[k0];
        rawC = xbuf[(size_t)(pC >> 1) + lane];
        const f32x4* wr = (const f32x4*)(w1g + (size_t)k0 * NC);
        wC0 = wr[0]; wC1 = wr[1]; wC2 = wr[2]; wC3 = wr[3];
        if (k0 + 1 < k1) pN = pd[k0 + 1];
    }
    #pragma unroll 2
    for (int k = k0; k < k1; ++k) {
        unsigned pN2 = (k + 2 < k1) ? pd[k + 2] : 0u;
        float rawN = 0.f;
        f32x4 wN0 = 0.f, wN1 = 0.f, wN2 = 0.f, wN3 = 0.f;
        if (k + 1 < k1) {
            rawN = xbuf[(size_t)(pN >> 1) + lane];
            const f32x4* wr = (const f32x4*)(w1g + (size_t)(k + 1) * NC);
            wN0 = wr[0]; wN1 = wr[1]; wN2 = wr[2]; wN3 = wr[3];
        }
        float xv = (pC & 1u) ? (rawC - mu) * rs : rawC;
        acc[0]  += xv * wC0.x; acc[1]  += xv * wC0.y; acc[2]  += xv * wC0.z; acc[3]  += xv * wC0.w;
        acc[4]  += xv * wC1.x; acc[5]  += xv * wC1.y; acc[6]  += xv * wC1.z; acc[7]  += xv * wC1.w;
        acc[8]  += xv * wC2.x; acc[9]  += xv * wC2.y; acc[10] += xv * wC2.z; acc[11] += xv * wC2.w;
        acc[12] += xv * wC3.x; acc[13] += xv * wC3.y; acc[14] += xv * wC3.z; acc[15] += xv * wC3.w;
        pC = pN; pN = pN2; rawC = rawN;
        wC0 = wN0; wC1 = wN1; wC2 = wN2; wC3 = wN3;
    }

    float h[NC];
    #pragma unroll
    for (int c = 0; c < NC; ++c) h[c] = elu_fast(acc[c]);

    float hf[NC];
    {
        const f32x4* b2r = (const f32x4*)(b2 + (size_t)n * NC);
        f32x4 a = b2r[0], b = b2r[1], c = b2r[2], d = b2r[3];
        hf[0]=a.x; hf[1]=a.y; hf[2]=a.z; hf[3]=a.w;
        hf[4]=b.x; hf[5]=b.y; hf[6]=b.z; hf[7]=b.w;
        hf[8]=c.x; hf[9]=c.y; hf[10]=c.z; hf[11]=c.w;
        hf[12]=d.x; hf[13]=d.y; hf[14]=d.z; hf[15]=d.w;
    }
    const float* w2f = w2 + (size_t)wid * NC * NC;
    #pragma unroll
    for (int c = 0; c < NC; ++c) {
        const f32x4* w2r = (const f32x4*)(w2f + c * NC);
        f32x4 a = w2r[0], b = w2r[1], cc = w2r[2], d = w2r[3];
        float hc = h[c];
        hf[0]  += hc * a.x;  hf[1]  += hc * a.y;  hf[2]  += hc * a.z;  hf[3]  += hc * a.w;
        hf[4]  += hc * b.x;  hf[5]  += hc * b.y;  hf[6]  += hc * b.z;  hf[7]  += hc * b.w;
        hf[8]  += hc * cc.x; hf[9]  += hc * cc.y; hf[10] += hc * cc.z; hf[11] += hc * cc.w;
        hf[12] += hc * d.x;  hf[13] += hc * d.y;  hf[14] += hc * d.z;  hf[15] += hc * d.w;
    }

    f32x4 o0, o1, o2, o3;
    o0.x = elu_fast(hf[0]);  o0.y = elu_fast(hf[1]);
    o0.z = elu_fast(hf[2]);  o0.w = elu_fast(hf[3]);
    o1.x = elu_fast(hf[4]);  o1.y = elu_fast(hf[5]);
    o1.z = elu_fast(hf[6]);  o1.w = elu_fast(hf[7]);
    o2.x = elu_fast(hf[8]);  o2.y = elu_fast(hf[9]);
    o2.z = elu_fast(hf[10]); o2.w = elu_fast(hf[11]);
    o3.x = elu_fast(hf[12]); o3.y = elu_fast(hf[13]);
    o3.z = elu_fast(hf[14]); o3.w = elu_fast(hf[15]);
    f32x4* h2r = (f32x4*)(h2 + ((size_t)wid * NB + lane) * NC);
    __builtin_nontemporal_store(o0, h2r + 0);
    __builtin_nontemporal_store(o1, h2r + 1);
    __builtin_nontemporal_store(o2, h2r + 2);
    __builtin_nontemporal_store(o3, h2r + 3);
}

// Per src node (one wave, lane=batch): h2 row reused across out-edges.
__global__ __launch_bounds__(512, 4) void k_edge(
    float* __restrict__ xeD, const float* __restrict__ xT,
    const float* __restrict__ sums, float* __restrict__ sumsOut,
    const float* __restrict__ h2,
    const float* __restrict__ w3g, const float* __restrict__ b3g,
    const float* __restrict__ c3,
    const int* __restrict__ rp, const unsigned* __restrict__ pe2)
{
    __shared__ float shs[512], shq[512];
    int lane = threadIdx.x & 63;
    int s = __builtin_amdgcn_readfirstlane((int)(blockIdx.x * 8 + (threadIdx.x >> 6)));
    float lsum = 0.f, lsq = 0.f;
    if (s < NS) {
        float x0v = xT[(size_t)s * NB + lane];
        int k0 = __builtin_amdgcn_readfirstlane(rp[s]);
        int k1 = __builtin_amdgcn_readfirstlane(rp[s + 1]);
        if (s < NI) {
            // all out-edges are input edges: v = x0 + precomputed const
            for (int k = k0; k < k1; ++k) {
                float v = x0v + c3[k];
                lsum += v; lsq += v * v;
            }
        } else {
            const float inv = 1.0f / (float)NE;
            float mu = sums[lane] * inv;
            float rs = rsqrtf(sums[64 + lane] * inv - mu * mu + LN_EPS);
            float hv[NC];
            {
                const f32x4* hr = (const f32x4*)(h2 + (((size_t)(s - NI)) * NB + lane) * NC);
                f32x4 a = __builtin_nontemporal_load(hr + 0);
                f32x4 b = __builtin_nontemporal_load(hr + 1);
                f32x4 c = __builtin_nontemporal_load(hr + 2);
                f32x4 d = __builtin_nontemporal_load(hr + 3);
                hv[0]=a.x; hv[1]=a.y; hv[2]=a.z; hv[3]=a.w;
                hv[4]=b.x; hv[5]=b.y; hv[6]=b.z; hv[7]=b.w;
                hv[8]=c.x; hv[9]=c.y; hv[10]=c.z; hv[11]=c.w;
                hv[12]=d.x; hv[13]=d.y; hv[14]=d.z; hv[15]=d.w;
            }
            unsigned posC = 0, posN = 0;
            float oldC = 0.f, bC = 0.f;
            f32x4 wc0 = 0.f, wc1 = 0.f, wc2 = 0.f, wc3 = 0.f;
            if (k0 < k1) {
                posC = pe2[k0];
                oldC = xeD[(size_t)posC + lane];
                const f32x4* wr = (const f32x4*)(w3g + (size_t)k0 * NC);
                wc0 = wr[0]; wc1 = wr[1]; wc2 = wr[2]; wc3 = wr[3];
                bC = b3g[k0];
                if (k0 + 1 < k1) posN = pe2[k0 + 1];
            }
            #pragma unroll 2
            for (int k = k0; k < k1; ++k) {
                unsigned posN2 = (k + 2 < k1) ? pe2[k + 2] : 0u;
                float oldN = 0.f, bN = 0.f;
                f32x4 wn0 = 0.f, wn1 = 0.f, wn2 = 0.f, wn3 = 0.f;
                if (k + 1 < k1) {
                    oldN = xeD[(size_t)posN + lane];
                    const f32x4* wr = (const f32x4*)(w3g + (size_t)(k + 1) * NC);
                    wn0 = wr[0]; wn1 = wr[1]; wn2 = wr[2]; wn3 = wr[3];
                    bN = b3g[k + 1];
                }
                float xl = (oldC - mu) * rs;   // all unmasked here
                float v = bC + xl;
                v += hv[0]*wc0.x + hv[1]*wc0.y + hv[2]*wc0.z + hv[3]*wc0.w;
                v += hv[4]*wc1.x + hv[5]*wc1.y + hv[6]*wc1.z + hv[7]*wc1.w;
                v += hv[8]*wc2.x + hv[9]*wc2.y + hv[10]*wc2.z + hv[11]*wc2.w;
                v += hv[12]*wc3.x + hv[13]*wc3.y + hv[14]*wc3.z + hv[15]*wc3.w;
                __builtin_nontemporal_store(v, &xeD[(size_t)posC + lane]);
                lsum += v; lsq += v * v;
                posC = posN; posN = posN2; oldC = oldN; bC = bN;
                wc0 = wn0; wc1 = wn1; wc2 = wn2; wc3 = wn3;
            }
        }
    }
    shs[threadIdx.x] = lsum; shq[threadIdx.x] = lsq;
    __syncthreads();
    int t = threadIdx.x;
    if (t < 64) {
        float ts = 0.f;
        #pragma unroll
        for (int w = 0; w < 8; ++w) ts += shs[w * 64 + t];
        atomicAdd(&sumsOut[t], ts);
    } else if (t < 128) {
        int l = t - 64;
        float tq = 0.f;
        #pragma unroll
        for (int w = 0; w < 8; ++w) tq += shq[w * 64 + l];
        atomicAdd(&sumsOut[64 + l], tq);
    }
}

__global__ __launch_bounds__(256) void k_out(
    const float* __restrict__ xbuf, const float* __restrict__ sums,
    const int* __restrict__ src, const int* __restrict__ posOf,
    const float* __restrict__ scale, const float* __restrict__ bias,
    const int* __restrict__ last_edge, const float* __restrict__ has,
    float* __restrict__ out)
{
    __shared__ float t[64][65];
    int n0 = blockIdx.x * 64;
    int lane = threadIdx.x & 63, w = threadIdx.x >> 6;
    const float inv = 1.0f / (float)NE;
    float mu = sums[lane] * inv;
    float rs = rsqrtf(sums[64 + lane] * inv - mu * mu + LN_EPS);
    for (int nn = w; nn < 64; nn += 4) {
        int n = n0 + nn;
        float val = 0.f;
        if (n < NN) {
            int le = last_edge[n];
            int s = src[le];
            float x0v = xbuf[(size_t)s * NB + lane];
            float xn = (xbuf[(size_t)XEBASE + (size_t)posOf[le] * NB + lane] - mu) * rs;
            float xf = (s < NI) ? x0v : xn;
            val = has[n] * (scale[le] * xf + bias[le]);
        }
        t[nn][lane] = val;
    }
    __syncthreads();
    for (int bb = w; bb < 64; bb += 4) {
        int n = n0 + lane;
        if (n < NN) out[(size_t)bb * NN + n] = t[lane][bb];
    }
}

extern "C" void kernel_launch(void* const* d_in, const int* in_sizes, int n_in,
                              void* d_out, int out_size, void* d_ws, size_t ws_size,
                              hipStream_t stream) {
    const float* x     = (const float*)d_in[0];
    const float* w1    = (const float*)d_in[1];
    const float* b1    = (const float*)d_in[2];
    const float* w2    = (const float*)d_in[3];
    const float* b2    = (const float*)d_in[4];
    const float* w3    = (const float*)d_in[5];
    const float* b3    = (const float*)d_in[6];
    const float* scale = (const float*)d_in[7];
    const float* bias  = (const float*)d_in[8];
    const int*   src   = (const int*)d_in[9];
    const int*   dst   = (const int*)d_in[10];
    const int*   last  = (const int*)d_in[13];
    const float* has   = (const float*)d_in[14];
    float* out = (float*)d_out;

    char* p = (char*)d_ws;
    auto alloc = [&](size_t bytes) {
        char* r = p;
        p += (bytes + 255) & ~(size_t)255;
        return r;
    };
    float* xbuf  = (float*)alloc(((size_t)NN + NE) * NB * 4);   // [xT | xeD]
    float* xeD   = xbuf + XEBASE;
    float* h2    = (float*)alloc((size_t)NF * NB * NC * 4);
    float* accum = (float*)alloc((NLAYERS + 1) * 128 * 4);
    float* w1g   = (float*)alloc((size_t)NE * NC * 4);
    float* w3g   = (float*)alloc((size_t)NE * NC * 4);
    float* b3g   = (float*)alloc((size_t)NE * 4);
    float* c3    = (float*)alloc((size_t)NE * 4);
    unsigned* pd  = (unsigned*)alloc((size_t)NE * 4);
    unsigned* pe2 = (unsigned*)alloc((size_t)NE * 4);
    int* rp_s  = (int*)alloc((NS + 1) * 4);
    int* rp_d  = (int*)alloc((NF + 1) * 4);
    int* el_s  = (int*)alloc((size_t)NE * 4);
    int* el_d  = (int*)alloc((size_t)NE * 4);
    int* posOf = (int*)alloc((size_t)NE * 4);
    int* off_s = (int*)alloc(NS * 4);
    int* off_d = (int*)alloc(NF * 4);
    int* cs    = (int*)alloc(NS * 4);
    int* cd    = (int*)alloc(NF * 4);
    int* foCtr = (int*)alloc(4);

    hipMemsetAsync(cs, 0, NS * 4, stream);
    hipMemsetAsync(cd, 0, NF * 4, stream);
    k_transpose<<<TILE_BLOCKS, 256, 0, stream>>>(x, xbuf);
    k_count<<<(NE + 255) / 256, 256, 0, stream>>>(src, dst, cs, cd);
    k_scan<<<1, 1024, 0, stream>>>(cs, rp_s, NS);
    k_scan<<<1, 1024, 0, stream>>>(cd, rp_d, NF);
    k_copyoff<<<(NS + 255) / 256, 256, 0, stream>>>(rp_s, rp_d, off_s, off_d, foCtr);
    k_fill<<<(NE + 255) / 256, 256, 0, stream>>>(src, dst, off_s, off_d, foCtr,
                                                 el_s, el_d, posOf);
    k_permute<<<(NE + 255) / 256, 256, 0, stream>>>(src, w1, w3, b3, b2, rp_d,
                                                    el_d, el_s, posOf,
                                                    pd, pe2, w1g, w3g, b3g, c3);
    k_init_xe<<<(int)(((size_t)NE * NB + 255) / 256), 256, 0, stream>>>(xbuf, src, posOf,
                                                                        xeD, accum);

    for (int L = 0; L < NLAYERS; ++L) {
        k_node<<<NODE_BLOCKS, 256, 0, stream>>>(xbuf, accum + L * 128,
                                                w1g, b1, w2, b2, rp_d, pd, h2);
        k_edge<<<EDGE_BLOCKS, 512, 0, stream>>>(xeD, xbuf, accum + L * 128,
                                                accum + (L + 1) * 128,
                                                h2, w3g, b3g, c3, rp_s, pe2);
    }
    k_out<<<TILE_BLOCKS, 256, 0, stream>>>(xbuf, accum + NLAYERS * 128, src, posOf,
                                           scale, bias, last, has, out);
}